// Round 2
// baseline (2880.327 us; speedup 1.0000x reference)
//
#include <hip/hip_runtime.h>
#include <stdint.h>

// RotEncoderMLP: orbit-stack -> c4conv(7->2048)+relu -> c4conv(2048->2048)+LN+relu -> c4conv(2048->512)
// All c4convs are GEMMs vs block-circulant weights: Bt[(g,i)][(h,j)] = w[(h-g)&3][i][j].
// L2/L3 run as bf16 MFMA GEMMs (m97 structure: 128x128 tile, BK=64, global_load_lds w=16).
// M-chunked pipeline: per-chunk scratch sized to fit the ACTUAL ws_size (round-1 crash
// was an OOB write past d_ws from assuming 546 MB of scratch).

#define HID 2048
#define KDIM 8192
#define MROWS 10240

typedef float floatx4 __attribute__((ext_vector_type(4)));
typedef __bf16 bf16x8 __attribute__((ext_vector_type(8)));

__device__ __forceinline__ unsigned short f2bf(float f) {
  union { float f; unsigned int u; } v; v.f = f;
  unsigned int r = v.u + 0x7fffu + ((v.u >> 16) & 1u);  // RNE
  return (unsigned short)(r >> 16);
}

// ---------- f32 -> bf16 weight convert ----------
__global__ __launch_bounds__(256) void cvt_bf16_kernel(const float* __restrict__ s,
                                                       unsigned short* __restrict__ d, int n4) {
  int i = blockIdx.x * 256 + threadIdx.x;
  if (i >= n4) return;
  float4 v = ((const float4*)s)[i];
  ushort4 o;
  o.x = f2bf(v.x); o.y = f2bf(v.y); o.z = f2bf(v.z); o.w = f2bf(v.w);
  ((ushort4*)d)[i] = o;
}

// ---------- orbit-stack + layer1 + relu -> h1 bf16 (chunk-local rows x 8192; col = g*2048+i) ----------
__global__ __launch_bounds__(256) void layer1_kernel(const float* __restrict__ ins,
                                                     const float* __restrict__ w1,
                                                     const float* __restrict__ b1,
                                                     unsigned short* __restrict__ h1,
                                                     int row0) {
  __shared__ float orbs[32][28];
  int t = threadIdx.x;
  int b0 = blockIdx.x * 32;            // chunk-local
  int g = blockIdx.y >> 3;
  int i = (blockIdx.y & 7) * 256 + t;
  if (t < 32) {
    const float* x = ins + (size_t)(row0 + b0 + t) * 25;
    float v[25];
#pragma unroll
    for (int p = 0; p < 25; ++p) v[p] = x[p];
    float* o = orbs[t];
    o[0] = v[12]; o[7] = v[12]; o[14] = v[12]; o[21] = v[12];  // center, all 4 rotations
#pragma unroll
    for (int r = 0; r < 2; ++r)
#pragma unroll
      for (int c = 0; c < 3; ++c) {
        int m = 1 + r * 3 + c;
        o[m]      = v[r * 5 + c];              // rot^0: x[r][c]
        o[7 + m]  = v[c * 5 + (4 - r)];        // rot^1: x[c][4-r]
        o[14 + m] = v[(4 - r) * 5 + (4 - c)];  // rot^2
        o[21 + m] = v[(4 - c) * 5 + r];        // rot^3
      }
  }
  __syncthreads();
  float w[4][7];
#pragma unroll
  for (int r = 0; r < 4; ++r)
#pragma unroll
    for (int j = 0; j < 7; ++j) w[r][j] = w1[(r * HID + i) * 7 + j];
  float bias = b1[i];
  for (int s = 0; s < 32; ++s) {
    float acc = bias;
#pragma unroll
    for (int hh = 0; hh < 4; ++hh) {
      int r = (hh - g) & 3;
#pragma unroll
      for (int j = 0; j < 7; ++j) acc += w[r][j] * orbs[s][hh * 7 + j];
    }
    h1[(size_t)(b0 + s) * KDIM + g * HID + i] = f2bf(fmaxf(acc, 0.f));
  }
}

// ---------- bf16 MFMA GEMM vs block-circulant weights, bias fused, f32 out ----------
// C[m][n] = bias[n & nmask] + sum_k A[m][k] * Bw[((k>>11)-(n>>n_shift))&3][n&nmask][k&2047]
#define BM 128
#define BN 128
#define BK 64

__global__ __launch_bounds__(256) void gemm_c4(const unsigned short* __restrict__ A,
                                               const unsigned short* __restrict__ Bw,
                                               const float* __restrict__ bias,
                                               float* __restrict__ C,
                                               int N, int n_shift, int nmask, size_t blk_stride) {
  __shared__ __align__(16) unsigned short As[BM * BK];
  __shared__ __align__(16) unsigned short Bs[BN * BK];
  int tid = threadIdx.x;
  int wave = tid >> 6;
  int lane = tid & 63;
  int m0 = blockIdx.y * BM;
  int n0 = blockIdx.x * BN;
  int g = n0 >> n_shift;
  int n_in_g = n0 & nmask;

  int srow = wave * 8 + (lane >> 3);  // staging row (per 32-row quarter q)
  int scol = (lane & 7) * 8;          // staging element col (16B chunks)

  const unsigned short* Ag  = A + (size_t)(m0 + srow) * KDIM + scol;
  const unsigned short* Bg0 = Bw + (size_t)(n_in_g + srow) * HID + scol;

  int wm = (wave >> 1) * 64;
  int wn = (wave & 1) * 64;
  int lr = lane & 15;
  int lq = lane >> 4;

  const floatx4 fz = {0.f, 0.f, 0.f, 0.f};
  floatx4 acc[4][4];
#pragma unroll
  for (int a = 0; a < 4; ++a)
#pragma unroll
    for (int b = 0; b < 4; ++b) acc[a][b] = fz;

  for (int k0 = 0; k0 < KDIM; k0 += BK) {
    int blk = ((k0 >> 11) - g) & 3;
    const unsigned short* Agk = Ag + k0;
    const unsigned short* Bgk = Bg0 + (size_t)blk * blk_stride + (k0 & (HID - 1));
#pragma unroll
    for (int q = 0; q < 4; ++q)
      __builtin_amdgcn_global_load_lds(
          (const __attribute__((address_space(1))) void*)(Agk + (size_t)q * 32 * KDIM),
          (__attribute__((address_space(3))) void*)((char*)As + q * 4096 + wave * 1024),
          16, 0, 0);
#pragma unroll
    for (int q = 0; q < 4; ++q)
      __builtin_amdgcn_global_load_lds(
          (const __attribute__((address_space(1))) void*)(Bgk + (size_t)q * 32 * HID),
          (__attribute__((address_space(3))) void*)((char*)Bs + q * 4096 + wave * 1024),
          16, 0, 0);
    __syncthreads();
#pragma unroll
    for (int ks = 0; ks < 2; ++ks) {
      bf16x8 af[4], bfr[4];
#pragma unroll
      for (int mi = 0; mi < 4; ++mi)
        af[mi] = *(const bf16x8*)&As[(wm + mi * 16 + lr) * BK + ks * 32 + lq * 8];
#pragma unroll
      for (int ni = 0; ni < 4; ++ni)
        bfr[ni] = *(const bf16x8*)&Bs[(wn + ni * 16 + lr) * BK + ks * 32 + lq * 8];
#pragma unroll
      for (int mi = 0; mi < 4; ++mi)
#pragma unroll
        for (int ni = 0; ni < 4; ++ni)
          acc[mi][ni] = __builtin_amdgcn_mfma_f32_16x16x32_bf16(af[mi], bfr[ni], acc[mi][ni], 0, 0, 0);
    }
    __syncthreads();
  }

  // epilogue: C/D layout col=lane&15, row=(lane>>4)*4+r
#pragma unroll
  for (int ni = 0; ni < 4; ++ni) {
    int col = n0 + wn + ni * 16 + lr;
    float bv = bias[col & nmask];
#pragma unroll
    for (int mi = 0; mi < 4; ++mi) {
      int row = m0 + wm + mi * 16 + lq * 4;
#pragma unroll
      for (int r = 0; r < 4; ++r)
        C[(size_t)(row + r) * N + col] = acc[mi][ni][r] + bv;
    }
  }
}

// ---------- LayerNorm(+b2 already fused in GEMM) + relu -> h2 bf16 (in-place over h1c) ----------
__global__ __launch_bounds__(256) void ln_relu_kernel(const float* __restrict__ C2,
                                                      const float* __restrict__ ln_g,
                                                      const float* __restrict__ ln_b,
                                                      unsigned short* __restrict__ h2) {
  int t = threadIdx.x;
  size_t base = (size_t)blockIdx.x * HID;
  const float4* p = (const float4*)(C2 + base);
  float4 x0 = p[t];
  float4 x1 = p[256 + t];
  float s  = x0.x + x0.y + x0.z + x0.w + x1.x + x1.y + x1.z + x1.w;
  float sq = x0.x * x0.x + x0.y * x0.y + x0.z * x0.z + x0.w * x0.w +
             x1.x * x1.x + x1.y * x1.y + x1.z * x1.z + x1.w * x1.w;
#pragma unroll
  for (int off = 32; off > 0; off >>= 1) {
    s  += __shfl_down(s, off, 64);
    sq += __shfl_down(sq, off, 64);
  }
  __shared__ float rs[4], rq[4];
  int w = t >> 6, l = t & 63;
  if (l == 0) { rs[w] = s; rq[w] = sq; }
  __syncthreads();
  s  = rs[0] + rs[1] + rs[2] + rs[3];
  sq = rq[0] + rq[1] + rq[2] + rq[3];
  float mean = s * (1.f / HID);
  float var  = sq * (1.f / HID) - mean * mean;
  float rstd = rsqrtf(var + 1e-5f);
  const float4* gp = (const float4*)ln_g;
  const float4* bp = (const float4*)ln_b;
  float4 g0 = gp[t], g1 = gp[256 + t];
  float4 b0 = bp[t], b1 = bp[256 + t];
  ushort4 o0, o1;
  o0.x = f2bf(fmaxf((x0.x - mean) * rstd * g0.x + b0.x, 0.f));
  o0.y = f2bf(fmaxf((x0.y - mean) * rstd * g0.y + b0.y, 0.f));
  o0.z = f2bf(fmaxf((x0.z - mean) * rstd * g0.z + b0.z, 0.f));
  o0.w = f2bf(fmaxf((x0.w - mean) * rstd * g0.w + b0.w, 0.f));
  o1.x = f2bf(fmaxf((x1.x - mean) * rstd * g1.x + b1.x, 0.f));
  o1.y = f2bf(fmaxf((x1.y - mean) * rstd * g1.y + b1.y, 0.f));
  o1.z = f2bf(fmaxf((x1.z - mean) * rstd * g1.z + b1.z, 0.f));
  o1.w = f2bf(fmaxf((x1.w - mean) * rstd * g1.w + b1.w, 0.f));
  ((ushort4*)(h2 + base))[t] = o0;
  ((ushort4*)(h2 + base))[256 + t] = o1;
}

extern "C" void kernel_launch(void* const* d_in, const int* in_sizes, int n_in,
                              void* d_out, int out_size, void* d_ws, size_t ws_size,
                              hipStream_t stream) {
  const float* ins = (const float*)d_in[0];
  const float* w1  = (const float*)d_in[1];
  const float* b1  = (const float*)d_in[2];
  const float* w2  = (const float*)d_in[3];
  const float* b2  = (const float*)d_in[4];
  const float* w3  = (const float*)d_in[5];
  const float* b3  = (const float*)d_in[6];
  const float* lng = (const float*)d_in[7];
  const float* lnb = (const float*)d_in[8];
  float* out = (float*)d_out;
  char* ws = (char*)d_ws;

  // Persistent weights at base of ws: w2bf 33,554,432 B + w3bf 8,388,608 B.
  const size_t W2B = 33554432ull, W3B = 8388608ull;
  unsigned short* w2bf = (unsigned short*)(ws);
  unsigned short* w3bf = (unsigned short*)(ws + W2B);
  char* chunk_base = ws + W2B + W3B;

  // Pick smallest chunk count P (biggest chunks) whose scratch fits ws_size.
  // Per chunk: h1c bf16 Mc*8192*2  +  C2c f32 Mc*8192*4.
  static const int Pcand[10] = {1, 2, 4, 5, 8, 10, 16, 20, 40, 80};
  int P = 80;
  for (int pi = 0; pi < 10; ++pi) {
    size_t mc = (size_t)MROWS / Pcand[pi];
    size_t need = W2B + W3B + mc * KDIM * 2 + mc * KDIM * 4 + 256;
    if (need <= ws_size) { P = Pcand[pi]; break; }
  }
  const int Mc = MROWS / P;
  unsigned short* h1c = (unsigned short*)chunk_base;                       // Mc x 8192 bf16
  float*          C2c = (float*)(chunk_base + (size_t)Mc * KDIM * 2);     // Mc x 8192 f32

  cvt_bf16_kernel<<<16384, 256, 0, stream>>>(w2, w2bf, 4194304);
  cvt_bf16_kernel<<<4096, 256, 0, stream>>>(w3, w3bf, 1048576);

  for (int c = 0; c < P; ++c) {
    int row0 = c * Mc;
    layer1_kernel<<<dim3(Mc / 32, 32), 256, 0, stream>>>(ins, w1, b1, h1c, row0);
    // L2: M=Mc, N=8192, K=8192; bias b2 fused (pre-LN)
    gemm_c4<<<dim3(64, Mc / 128), 256, 0, stream>>>(h1c, w2bf, b2, C2c, 8192, 11, 2047,
                                                    (size_t)HID * HID);
    ln_relu_kernel<<<Mc * 4, 256, 0, stream>>>(C2c, lng, lnb, h1c);
    // L3: M=Mc, N=2048, K=8192; bias b3 fused
    gemm_c4<<<dim3(16, Mc / 128), 256, 0, stream>>>(h1c, w3bf, b3, out + (size_t)row0 * 2048,
                                                    2048, 9, 511, (size_t)512 * HID);
  }
}